// Round 5
// baseline (393.298 us; speedup 1.0000x reference)
//
#include <hip/hip_runtime.h>
#include <hip/hip_bf16.h>
#include <stdint.h>
#include <type_traits>

// ---------------------------------------------------------------------------
// MultiExpertMoELayer: opcode-routed 2-stage FFN chain.
//   op = argmax(x[0,0,0:8]);  for e in 0..1: x = gelu(x@W1[op,e]+b1)@W2[op,e]+b2
// Round 4 changes vs round 3/4:
//   1. 32x32x16 bf16 MFMA (2382 vs 2075 TF ceiling, half the instructions,
//      same bytes) -- MFMA floor per K-tile 2483 -> 2066 cyc.
//   2. 2 fat phases per K-tile (16 MFMA32/wave each) instead of 4 thin ones:
//      per-phase sync tax amortized 2x; 5 barriers/K-tile instead of 9.
//   3. Per-phase stage issue (half of S per phase), counted-wait-free top
//      (queue only holds current tile's loads at the boundary).
// R3 vs R4 A/B showed cover/issue-placement are NOT binding -> attack the
// per-phase sync tax and the MFMA rate itself.
// ---------------------------------------------------------------------------

typedef __attribute__((ext_vector_type(8))) short short8;    // 8 x bf16
typedef __attribute__((ext_vector_type(16))) float f32x16;   // 32x32 MFMA accum

#define VMCNT0 asm volatile("s_waitcnt vmcnt(0)" ::: "memory")
#define LGKM0  asm volatile("s_waitcnt lgkmcnt(0)" ::: "memory")
#define SBAR   __builtin_amdgcn_s_barrier()
#define SCHEDB __builtin_amdgcn_sched_barrier(0)

__device__ __forceinline__ unsigned short f2bf(float f) {
  union { float f; uint32_t u; } v; v.f = f;
  return (unsigned short)((v.u + 0x7fffu + ((v.u >> 16) & 1u)) >> 16);  // RNE
}

// jax.nn.gelu(approximate=True): 0.5x(1+tanh(sqrt(2/pi)(x+0.044715x^3)))
__device__ __forceinline__ float gelu_tanh(float x) {
  float u = 0.7978845608028654f * (x + 0.044715f * x * x * x);
  float e = __expf(2.0f * u);
  float t = 1.0f - 2.0f / (e + 1.0f);   // tanh(u), safe at +/-inf
  return 0.5f * x * (1.0f + t);
}

__device__ __forceinline__ void gload_lds16(const void* g, void* l) {
  __builtin_amdgcn_global_load_lds(
      (const __attribute__((address_space(1))) void*)g,
      (__attribute__((address_space(3))) void*)l, 16, 0, 0);
}

// --------------------------- routing ---------------------------------------
__global__ void route_kernel(const float* __restrict__ x, int* __restrict__ op_out) {
  if (threadIdx.x == 0) {
    int best = 0; float bv = x[0];
    for (int i = 1; i < 8; ++i) { float v = x[i]; if (v > bv) { bv = v; best = i; } }
    *op_out = best;   // first-max wins, matches jnp.argmax
  }
}

// --------------------------- converts --------------------------------------
__global__ void cvt_x_kernel(const float* __restrict__ x, unsigned short* __restrict__ xb, int n4) {
  int i = blockIdx.x * blockDim.x + threadIdx.x;
  if (i >= n4) return;
  float4 v = ((const float4*)x)[i];
  ushort4 o; o.x = f2bf(v.x); o.y = f2bf(v.y); o.z = f2bf(v.z); o.w = f2bf(v.w);
  ((ushort4*)xb)[i] = o;
}

// in: fp32 [R][C] (opcode/expert-selected at runtime) -> out: bf16 [C][R]
__global__ void transpose_cvt_kernel(const float* __restrict__ Wbase,
                                     unsigned short* __restrict__ outb,
                                     const int* __restrict__ op_ptr,
                                     int R, int C, int expert) {
  __shared__ float tile[64][65];
  const int op = *op_ptr;
  const float* W = Wbase + ((size_t)op * 2 + (size_t)expert) * (size_t)R * (size_t)C;
  const int tr = blockIdx.y, tc = blockIdx.x;
  const int t = threadIdx.x;
  {
    const int r  = t >> 2;
    const int c0 = (t & 3) * 16;
    const float* src = W + (size_t)(tr * 64 + r) * C + tc * 64 + c0;
#pragma unroll
    for (int j = 0; j < 16; j += 4) {
      float4 v = *(const float4*)(src + j);
      tile[r][c0 + j]     = v.x;
      tile[r][c0 + j + 1] = v.y;
      tile[r][c0 + j + 2] = v.z;
      tile[r][c0 + j + 3] = v.w;
    }
  }
  __syncthreads();
  {
    const int c  = t >> 2;
    const int r0 = (t & 3) * 16;
    unsigned short* dst = outb + (size_t)(tc * 64 + c) * R + tr * 64 + r0;
#pragma unroll
    for (int j = 0; j < 16; j += 4) {
      ushort4 o;
      o.x = f2bf(tile[r0 + j][c]);
      o.y = f2bf(tile[r0 + j + 1][c]);
      o.z = f2bf(tile[r0 + j + 2][c]);
      o.w = f2bf(tile[r0 + j + 3][c]);
      *(ushort4*)(dst + j) = o;
    }
  }
}

// --------------------------- 32x32 phase GEMM -------------------------------
// C = A @ Bt^T + bias [,gelu].  A: [M][K] bf16, Bt: [N][K] bf16.
// BM=256, BN=BN64*64, BK=64. 8 waves WR x WC; per-wave (BM/WR) x (BN/WC).
// Frags 32x32x16: lane holds row/col = lane&31, k = 8*(lane>>5)+j.
// LDS: A [256][64] + B [BN][64] bf16; 16B chunk c of row r at c ^ (r&7).

template<int BN64>
__device__ __forceinline__ void stage_one(
    int j, const unsigned short* __restrict__ Ab,
    const unsigned short* __restrict__ Bb,
    int K, int kb, short* __restrict__ dst, int tid) {
  constexpr int ABK = 256 * 64;   // shorts in A region
  if (j < 4) {                    // A: 4 instrs cover 256x64
    const int ci = j * 512 + tid;
    const int row = ci >> 3;
    const int gc = (ci & 7) ^ (row & 7);
    gload_lds16(Ab + (size_t)row * K + kb + gc * 8, dst + ci * 8);
  } else {                        // B: BN64 instrs cover BN x 64
    const int cj = (j - 4) * 512 + tid;
    const int row = cj >> 3;
    const int gc = (cj & 7) ^ (row & 7);
    gload_lds16(Bb + (size_t)row * K + kb + gc * 8, dst + ABK + cj * 8);
  }
}

template<int BN64, int WR, bool GELU, typename OUT_T>
__global__ __launch_bounds__(512, 2) void gemm32(
    const unsigned short* __restrict__ A,
    const unsigned short* __restrict__ Bt,
    const float* __restrict__ bias_base,     // [8][2][N]
    const int* __restrict__ op_ptr, int expert,
    OUT_T* __restrict__ Cout, int M, int N, int K, int nbn)
{
  constexpr int BM = 256, BK = 64;
  constexpr int BN = BN64 * 64;
  constexpr int WC = 8 / WR;              // wave grid WR x WC
  constexpr int MF = (BM / WR) / 32;      // 32-row frags per wave (4 or 2)
  constexpr int NF = (BN / WC) / 32;      // 32-col frags per wave (2)
  constexpr int MH = MF / 2;              // M-frags per phase
  constexpr int S  = 4 + BN64;            // stage instrs per K-tile (8 or 6)
  constexpr int H  = S / 2;               // stage instrs issued per phase
  constexpr int BUF = (BM + BN) * BK;     // shorts per double-buffer half
  __shared__ short smem[2 * BUF];

  const int tid  = threadIdx.x;
  const int wid  = tid >> 6, lane = tid & 63;
  const int wm   = wid / WC, wn = wid % WC;
  const int l31  = lane & 31, lh = lane >> 5;

  // XCD-aware bijective swizzle (nwg % 8 == 0), bm-major within an XCD chunk
  const int nwg = gridDim.x;
  const int id  = blockIdx.x;
  const int s   = (id & 7) * (nwg >> 3) + (id >> 3);
  const int bm  = s / nbn, bn = s % nbn;

  const unsigned short* Ab = A  + (size_t)bm * BM * K;
  const unsigned short* Bb = Bt + (size_t)bn * BN * K;

  f32x16 acc[MF][NF] = {};

  // prologue: stage all of K-tile 0 into buffer 0
#pragma unroll
  for (int j = 0; j < S; ++j) stage_one<BN64>(j, Ab, Bb, K, 0, smem, tid);

  const int nkt = K / BK;
  for (int t = 0; t < nkt; ++t) {
    const char* cA = (const char*)(smem + (t & 1) * BUF);
    const char* cB = cA + BM * BK * 2;
    short* nxt = smem + ((t + 1) & 1) * BUF;
    const int kb = (t + 1) * BK;
    const bool pf = (t + 1) < nkt;

    // boundary: queue holds only tile t's loads here -> drain is cheap
    VMCNT0; SBAR; SCHEDB;

    short8 bf[NF][4];
#pragma unroll
    for (int mh = 0; mh < 2; ++mh) {
      // --- phase mh: ds_read cluster (issued before barrier, m201 order) ---
      short8 af[MH][4];
#pragma unroll
      for (int mm = 0; mm < MH; ++mm) {
        const int ra = wm * (BM / WR) + (mh * MH + mm) * 32 + l31;
#pragma unroll
        for (int ks = 0; ks < 4; ++ks) {
          const int ch = (ks * 2 + lh) ^ (ra & 7);
          af[mm][ks] = *(const short8*)(cA + ra * 128 + ch * 16);
        }
      }
      if (mh == 0) {
#pragma unroll
        for (int nf = 0; nf < NF; ++nf) {
          const int rb = wn * (BN / WC) + nf * 32 + l31;
#pragma unroll
          for (int ks = 0; ks < 4; ++ks) {
            const int ch = (ks * 2 + lh) ^ (rb & 7);
            bf[nf][ks] = *(const short8*)(cB + rb * 128 + ch * 16);
          }
        }
      }
      // --- issue this phase's share of tile t+1's staging ---
      if (pf) {
#pragma unroll
        for (int j = 0; j < H; ++j)
          stage_one<BN64>(mh * H + j, Ab, Bb, K, kb, nxt, tid);
      }
      SBAR;                       // reads in flight during barrier wait
      LGKM0; SCHEDB;              // rule 18: sched_barrier after lgkmcnt
      __builtin_amdgcn_s_setprio(1);
#pragma unroll
      for (int mm = 0; mm < MH; ++mm)
#pragma unroll
        for (int nf = 0; nf < NF; ++nf)
#pragma unroll
          for (int ks = 0; ks < 4; ++ks)
            acc[mh * MH + mm][nf] = __builtin_amdgcn_mfma_f32_32x32x16_bf16(
                af[mm][ks], bf[nf][ks], acc[mh * MH + mm][nf], 0, 0, 0);
      __builtin_amdgcn_s_setprio(0);
      SCHEDB; SBAR;
    }
  }

  // Epilogue: 32x32 C/D layout col=lane&31, row=(r&3)+8*(r>>2)+4*(lane>>5)
  const int op = *op_ptr;
  const float* bias = bias_base + ((size_t)op * 2 + (size_t)expert) * (size_t)N;
#pragma unroll
  for (int mf = 0; mf < MF; ++mf) {
    const int grow_base = bm * BM + wm * (BM / WR) + mf * 32 + 4 * lh;
#pragma unroll
    for (int nf = 0; nf < NF; ++nf) {
      const int gcol = bn * BN + wn * (BN / WC) + nf * 32 + l31;
      const float bv = bias[gcol];
#pragma unroll
      for (int r = 0; r < 16; ++r) {
        const int grow = grow_base + (r & 3) + 8 * (r >> 2);
        float v = acc[mf][nf][r] + bv;
        if constexpr (GELU) v = gelu_tanh(v);
        const size_t off = (size_t)grow * N + gcol;
        if constexpr (std::is_same<OUT_T, float>::value) Cout[off] = v;
        else Cout[off] = f2bf(v);
      }
    }
  }
}

// --------------------------- launcher ---------------------------------------
extern "C" void kernel_launch(void* const* d_in, const int* in_sizes, int n_in,
                              void* d_out, int out_size, void* d_ws, size_t ws_size,
                              hipStream_t stream) {
  const float* x  = (const float*)d_in[0];
  const float* W1 = (const float*)d_in[1];   // [8][2][1024][4096]
  const float* b1 = (const float*)d_in[2];   // [8][2][4096]
  const float* W2 = (const float*)d_in[3];   // [8][2][4096][1024]
  const float* b2 = (const float*)d_in[4];   // [8][2][1024]
  float* out = (float*)d_out;

  const int D = 1024, F = 4096, M = 8192;    // M = B*S = 4*2048

  // ws layout: [op int, pad 1KB][xb 16.8MB][w1t 16.8MB][w2t 16.8MB][h 67.1MB]
  char* ws = (char*)d_ws;
  int* op_ptr = (int*)ws;
  unsigned short* xb  = (unsigned short*)(ws + 1024);
  unsigned short* w1t = (unsigned short*)(ws + 1024 + (size_t)M * D * 2);
  unsigned short* w2t = (unsigned short*)(ws + 1024 + (size_t)M * D * 2 + (size_t)2 * D * F * 2);
  unsigned short* h   = (unsigned short*)(ws + 1024 + (size_t)M * D * 2 + (size_t)4 * D * F * 2);
  unsigned short* x1b = (unsigned short*)d_out;  // stage-0 output parked in d_out

  route_kernel<<<1, 64, 0, stream>>>(x, op_ptr);
  cvt_x_kernel<<<(M * D / 4 + 255) / 256, 256, 0, stream>>>(x, xb, M * D / 4);

  for (int e = 0; e < 2; ++e) {
    // W1[op,e]: [D][F] -> w1t[e]: [F][D]
    transpose_cvt_kernel<<<dim3(F / 64, D / 64), 256, 0, stream>>>(W1, w1t + (size_t)e * F * D, op_ptr, D, F, e);
    // W2[op,e]: [F][D] -> w2t[e]: [D][F]
    transpose_cvt_kernel<<<dim3(D / 64, F / 64), 256, 0, stream>>>(W2, w2t + (size_t)e * D * F, op_ptr, F, D, e);
  }

  // GEMM1: M=8192, N=4096, K=1024 -> BM=256, BN=256, waves 2Mx4N, grid 512
  // GEMM2: M=8192, N=1024, K=4096 -> BM=256, BN=128, waves 4Mx2N, grid 256
  // expert 0
  gemm32<4, 2, true,  unsigned short><<<(M/256)*(F/256), 512, 0, stream>>>(xb,  w1t,                 b1, op_ptr, 0, h,   M, F, D, F/256);
  gemm32<2, 4, false, unsigned short><<<(M/256)*(D/128), 512, 0, stream>>>(h,   w2t,                 b2, op_ptr, 0, x1b, M, D, F, D/128);
  // expert 1
  gemm32<4, 2, true,  unsigned short><<<(M/256)*(F/256), 512, 0, stream>>>(x1b, w1t + (size_t)F * D, b1, op_ptr, 1, h,   M, F, D, F/256);
  gemm32<2, 4, false, float         ><<<(M/256)*(D/128), 512, 0, stream>>>(h,   w2t + (size_t)D * F, b2, op_ptr, 1, out, M, D, F, D/128);
}

// Round 6
// 353.195 us; speedup vs baseline: 1.1135x; 1.1135x over previous
//
#include <hip/hip_runtime.h>
#include <hip/hip_bf16.h>
#include <stdint.h>
#include <type_traits>

// ---------------------------------------------------------------------------
// MultiExpertMoELayer: opcode-routed 2-stage FFN chain.
//   op = argmax(x[0,0,0:8]);  for e in 0..1: x = gelu(x@W1[op,e]+b1)@W2[op,e]+b2
// Round 6 (base = R3's 359us kernel, 16x16 MFMA, 4 thin phases):
//   1. GEMM2 reshaped BM=128/BN=256 (grid stays 256): A re-read 8x -> 4x
//      (-269 MB L3 traffic), bn-slow XCD chunks keep the 2MB B-panel in L2.
//      Old BN=128 demanded ~18 TB/s from L3 at the MFMA floor = structural
//      ceiling; schedule tweaks couldn't help (R2-R5 all ~360-390us).
//   2. route+cvt+4 transposes fused into ONE prep kernel (argmax recomputed
//      per block -- 8 L2-hot loads); GEMM blocks compute op inline too.
//      7 dispatches -> 5.
//   3. Reverted R5's 32x32 fat-phase experiment (VGPR pressure + vmcnt(0)
//      drain regressed it).
// Canary: absmax must stay exactly 0.01171875 (numerics unchanged).
// ---------------------------------------------------------------------------

typedef __attribute__((ext_vector_type(8))) short short8;   // 8 x bf16 (4 VGPR)
typedef __attribute__((ext_vector_type(4))) float f32x4;    // MFMA accum

#define LGKM0  asm volatile("s_waitcnt lgkmcnt(0)" ::: "memory")
#define SBAR   __builtin_amdgcn_s_barrier()
#define SCHEDB __builtin_amdgcn_sched_barrier(0)

template<int VM> __device__ __forceinline__ void wait_vm() {
  if constexpr (VM == 8)      asm volatile("s_waitcnt vmcnt(8)" ::: "memory");
  else if constexpr (VM == 6) asm volatile("s_waitcnt vmcnt(6)" ::: "memory");
  else                        asm volatile("s_waitcnt vmcnt(0)" ::: "memory");
}

__device__ __forceinline__ unsigned short f2bf(float f) {
  union { float f; uint32_t u; } v; v.f = f;
  return (unsigned short)((v.u + 0x7fffu + ((v.u >> 16) & 1u)) >> 16);  // RNE
}

// jax.nn.gelu(approximate=True): 0.5x(1+tanh(sqrt(2/pi)(x+0.044715x^3)))
__device__ __forceinline__ float gelu_tanh(float x) {
  float u = 0.7978845608028654f * (x + 0.044715f * x * x * x);
  float e = __expf(2.0f * u);
  float t = 1.0f - 2.0f / (e + 1.0f);   // tanh(u), safe at +/-inf
  return 0.5f * x * (1.0f + t);
}

__device__ __forceinline__ void gload_lds16(const void* g, void* l) {
  __builtin_amdgcn_global_load_lds(
      (const __attribute__((address_space(1))) void*)g,
      (__attribute__((address_space(3))) void*)l, 16, 0, 0);
}

// op = argmax(x[0,0,0:8]), first-max wins (matches jnp.argmax). Uniform,
// 8 L2-hot scalar loads -- cheap enough to recompute per block.
__device__ __forceinline__ int compute_op(const float* __restrict__ x) {
  int best = 0; float bv = x[0];
#pragma unroll
  for (int i = 1; i < 8; ++i) { float v = x[i]; if (v > bv) { bv = v; best = i; } }
  return best;
}

// --------------------------- fused prep kernel ------------------------------
// blocks [0, 4096)        : x fp32 -> bf16 (8 elems/thread)
// blocks [4096, 4096+4096): 4 transpose+cvt jobs of 1024 blocks each
//   job 0/1: W1[op,e] [1024][4096] -> w1t[e] [4096][1024]
//   job 2/3: W2[op,e] [4096][1024] -> w2t[e] [1024][4096]
__global__ __launch_bounds__(256) void prep_kernel(
    const float* __restrict__ x, const float* __restrict__ W1,
    const float* __restrict__ W2,
    unsigned short* __restrict__ xb, unsigned short* __restrict__ w1t,
    unsigned short* __restrict__ w2t) {
  __shared__ float tile[64][65];
  const int bid = blockIdx.x;
  const int t = threadIdx.x;
  if (bid < 4096) {
    const int i = bid * 256 + t;          // group-of-8 index
    const float4* xv = (const float4*)x;
    float4 v0 = xv[i * 2], v1 = xv[i * 2 + 1];
    ushort4 o0, o1;
    o0.x = f2bf(v0.x); o0.y = f2bf(v0.y); o0.z = f2bf(v0.z); o0.w = f2bf(v0.w);
    o1.x = f2bf(v1.x); o1.y = f2bf(v1.y); o1.z = f2bf(v1.z); o1.w = f2bf(v1.w);
    ((ushort4*)xb)[i * 2] = o0; ((ushort4*)xb)[i * 2 + 1] = o1;
    return;
  }
  const int op = compute_op(x);
  const int j = bid - 4096;
  const int job = j >> 10, w = j & 1023;
  const int e = job & 1;
  const bool isW1 = (job < 2);
  const int R = isW1 ? 1024 : 4096;
  const int C = isW1 ? 4096 : 1024;
  const float* W = (isW1 ? W1 : W2) + ((size_t)op * 2 + (size_t)e) * (size_t)R * C;
  unsigned short* dst0 = (isW1 ? w1t : w2t) + (size_t)e * 4096 * 1024;
  const int tc = w % (C >> 6), tr = w / (C >> 6);
  {
    const int r  = t >> 2;
    const int c0 = (t & 3) * 16;
    const float* src = W + (size_t)(tr * 64 + r) * C + tc * 64 + c0;
#pragma unroll
    for (int jj = 0; jj < 16; jj += 4) {
      float4 v = *(const float4*)(src + jj);
      tile[r][c0 + jj]     = v.x;
      tile[r][c0 + jj + 1] = v.y;
      tile[r][c0 + jj + 2] = v.z;
      tile[r][c0 + jj + 3] = v.w;
    }
  }
  __syncthreads();
  {
    const int c  = t >> 2;
    const int r0 = (t & 3) * 16;
    unsigned short* dp = dst0 + (size_t)(tc * 64 + c) * R + tr * 64 + r0;
#pragma unroll
    for (int jj = 0; jj < 16; jj += 4) {
      ushort4 o;
      o.x = f2bf(tile[r0 + jj][c]);
      o.y = f2bf(tile[r0 + jj + 1][c]);
      o.z = f2bf(tile[r0 + jj + 2][c]);
      o.w = f2bf(tile[r0 + jj + 3][c]);
      *(ushort4*)(dp + jj) = o;
    }
  }
}

// --------------------------- phase-split GEMM -------------------------------
// C = A @ Bt^T + bias [,gelu].  A: [M][K] bf16, Bt: [N][K] bf16.
// 8 waves fixed 2M x 4N; per-wave (BM/2) x 64.
// LDS per buffer: A [BM][64] + B [BN][64] bf16; 16B chunk c of row r stored
// at c ^ (r&7) (both-sides swizzle with pre-swizzled staging source).

template<int BM, int BN>
__device__ __forceinline__ void stage_tile_all(
    const unsigned short* __restrict__ Ab,
    const unsigned short* __restrict__ Bb,
    int K, int kb, short* __restrict__ dst, int tid) {
  constexpr int SA = BM / 64, SB = BN / 64, ABK = BM * 64;
#pragma unroll
  for (int j = 0; j < SA; ++j) {
    const int ci = j * 512 + tid;
    const int row = ci >> 3;
    const int gc = (ci & 7) ^ (row & 7);
    gload_lds16(Ab + (size_t)row * K + kb + gc * 8, dst + ci * 8);
  }
#pragma unroll
  for (int j = 0; j < SB; ++j) {
    const int cj = j * 512 + tid;
    const int row = cj >> 3;
    const int gc = (cj & 7) ^ (row & 7);
    gload_lds16(Bb + (size_t)row * K + kb + gc * 8, dst + ABK + cj * 8);
  }
}

template<int BM, int BN, bool SLOW_BM, bool KSPLIT, bool GELU, typename OUT_T>
__global__ __launch_bounds__(512, 2) void gemm16(
    const unsigned short* __restrict__ A,
    const unsigned short* __restrict__ Bt,
    const float* __restrict__ x_op,          // for inline op computation
    const float* __restrict__ bias_base,     // [8][2][N]
    int expert, OUT_T* __restrict__ Cout, int M, int N, int K)
{
  constexpr int BK = 64;
  constexpr int MR = BM / 32;             // 16-row frags per wave (8 or 4)
  constexpr int NR = 4;                   // 16-col frags per wave (BN/4/16)
  constexpr int MH = MR / 2;              // M-frags per M-half
  constexpr int S  = BM / 64 + BN / 64;   // stage instrs per K-tile (8 or 6)
  constexpr int BUF = (BM + BN) * BK;     // shorts per double-buffer half
  static_assert(BN == 256, "wave grid 2Mx4N assumes BN=256");
  __shared__ short smem[2 * BUF];

  const int tid  = threadIdx.x;
  const int wid  = tid >> 6, lane = tid & 63;
  const int wm   = wid >> 2, wn = wid & 3;
  const int lq   = lane >> 4, lr = lane & 15;

  // XCD-aware bijective swizzle (nwg % 8 == 0); slow index keeps the small
  // reused panel resident in the XCD's L2.
  const int nwg = gridDim.x;
  const int id  = blockIdx.x;
  const int s   = (id & 7) * (nwg >> 3) + (id >> 3);
  int bm, bn;
  if constexpr (SLOW_BM) { const int nbn = N / BN; bm = s / nbn; bn = s % nbn; }
  else                   { const int nbm = M / BM; bn = s / nbm; bm = s % nbm; }

  const unsigned short* Ab = A  + (size_t)bm * BM * K;
  const unsigned short* Bb = Bt + (size_t)bn * BN * K;

  f32x4 acc[MR][NR] = {};

  // prologue: stage all of K-tile 0 into buffer 0
  stage_tile_all<BM, BN>(Ab, Bb, K, 0, smem, tid);

  const int nkt = K / BK;
  for (int t = 0; t < nkt; ++t) {
    const char* cA = (const char*)(smem + (t & 1) * BUF);
    const char* cB = cA + BM * BK * 2;
    short* nxt = smem + ((t + 1) & 1) * BUF;

    // tile top: issue ALL of tile t+1's stages (full-tile latency cover),
    // then counted wait for tile t's loads only (T4: t+1 stays in flight).
    if (t + 1 < nkt) { stage_tile_all<BM, BN>(Ab, Bb, K, (t + 1) * BK, nxt, tid); wait_vm<S>(); }
    else             { wait_vm<0>(); }
    SBAR; SCHEDB;

    if constexpr (KSPLIT) {
      // 4 phases: (ks, mh), 16 MFMA each  [GEMM1, MR=8]
#pragma unroll
      for (int ks = 0; ks < 2; ++ks) {
        short8 bf[NR];
#pragma unroll
        for (int mh = 0; mh < 2; ++mh) {
          short8 af[MH];
#pragma unroll
          for (int mm = 0; mm < MH; ++mm) {
            const int ra = wm * (BM / 2) + (mh * MH + mm) * 16 + lr;
            const int ch = ((ks << 2) | lq) ^ (ra & 7);
            af[mm] = *(const short8*)(cA + ra * 128 + ch * 16);
          }
          if (mh == 0) {
#pragma unroll
            for (int n = 0; n < NR; ++n) {
              const int rb = wn * 64 + n * 16 + lr;
              const int ch = ((ks << 2) | lq) ^ (rb & 7);
              bf[n] = *(const short8*)(cB + rb * 128 + ch * 16);
            }
          }
          SBAR;
          LGKM0; SCHEDB;
          __builtin_amdgcn_s_setprio(1);
#pragma unroll
          for (int mm = 0; mm < MH; ++mm)
#pragma unroll
            for (int n = 0; n < NR; ++n)
              acc[mh * MH + mm][n] = __builtin_amdgcn_mfma_f32_16x16x32_bf16(
                  af[mm], bf[n], acc[mh * MH + mm][n], 0, 0, 0);
          __builtin_amdgcn_s_setprio(0);
          SCHEDB; SBAR;
        }
      }
    } else {
      // 2 phases: mh only, both ks inside, 16 MFMA each  [GEMM2, MR=4]
      short8 bf[NR][2];
#pragma unroll
      for (int mh = 0; mh < 2; ++mh) {
        short8 af[MH][2];
#pragma unroll
        for (int mm = 0; mm < MH; ++mm) {
          const int ra = wm * (BM / 2) + (mh * MH + mm) * 16 + lr;
#pragma unroll
          for (int ks = 0; ks < 2; ++ks) {
            const int ch = ((ks << 2) | lq) ^ (ra & 7);
            af[mm][ks] = *(const short8*)(cA + ra * 128 + ch * 16);
          }
        }
        if (mh == 0) {
#pragma unroll
          for (int n = 0; n < NR; ++n) {
            const int rb = wn * 64 + n * 16 + lr;
#pragma unroll
            for (int ks = 0; ks < 2; ++ks) {
              const int ch = ((ks << 2) | lq) ^ (rb & 7);
              bf[n][ks] = *(const short8*)(cB + rb * 128 + ch * 16);
            }
          }
        }
        SBAR;
        LGKM0; SCHEDB;
        __builtin_amdgcn_s_setprio(1);
#pragma unroll
        for (int mm = 0; mm < MH; ++mm)
#pragma unroll
          for (int n = 0; n < NR; ++n)
#pragma unroll
            for (int ks = 0; ks < 2; ++ks)
              acc[mh * MH + mm][n] = __builtin_amdgcn_mfma_f32_16x16x32_bf16(
                  af[mm][ks], bf[n][ks], acc[mh * MH + mm][n], 0, 0, 0);
        __builtin_amdgcn_s_setprio(0);
        SCHEDB; SBAR;
      }
    }
  }

  // Epilogue: C/D layout col=lane&15, row=(lane>>4)*4+reg [m89-verified]
  const int op = compute_op(x_op);
  const float* bias = bias_base + ((size_t)op * 2 + (size_t)expert) * (size_t)N;
#pragma unroll
  for (int f = 0; f < MR; ++f) {
    const int grow0 = bm * BM + wm * (BM / 2) + f * 16 + lq * 4;
#pragma unroll
    for (int n = 0; n < NR; ++n) {
      const int gcol = bn * BN + wn * 64 + n * 16 + lr;
      const float bv = bias[gcol];
#pragma unroll
      for (int r = 0; r < 4; ++r) {
        float v = acc[f][n][r] + bv;
        if constexpr (GELU) v = gelu_tanh(v);
        const size_t off = (size_t)(grow0 + r) * N + gcol;
        if constexpr (std::is_same<OUT_T, float>::value) Cout[off] = v;
        else Cout[off] = f2bf(v);
      }
    }
  }
}

// --------------------------- launcher ---------------------------------------
extern "C" void kernel_launch(void* const* d_in, const int* in_sizes, int n_in,
                              void* d_out, int out_size, void* d_ws, size_t ws_size,
                              hipStream_t stream) {
  const float* x  = (const float*)d_in[0];
  const float* W1 = (const float*)d_in[1];   // [8][2][1024][4096]
  const float* b1 = (const float*)d_in[2];   // [8][2][4096]
  const float* W2 = (const float*)d_in[3];   // [8][2][4096][1024]
  const float* b2 = (const float*)d_in[4];   // [8][2][1024]
  float* out = (float*)d_out;

  const int D = 1024, F = 4096, M = 8192;    // M = B*S = 4*2048

  // ws layout: [xb 16.8MB][w1t 16.8MB][w2t 16.8MB][h 67.1MB]
  char* ws = (char*)d_ws;
  unsigned short* xb  = (unsigned short*)ws;
  unsigned short* w1t = (unsigned short*)(ws + (size_t)M * D * 2);
  unsigned short* w2t = (unsigned short*)(ws + (size_t)M * D * 2 + (size_t)2 * D * F * 2);
  unsigned short* h   = (unsigned short*)(ws + (size_t)M * D * 2 + (size_t)4 * D * F * 2);
  unsigned short* x1b = (unsigned short*)d_out;  // stage-0 output parked in d_out

  // one fused prep dispatch: cvt(x) + 4 transpose/cvt jobs
  prep_kernel<<<4096 + 4 * 1024, 256, 0, stream>>>(x, W1, W2, xb, w1t, w2t);

  // GEMM1: M=8192,N=4096,K=1024  BM=256,BN=256, grid 512, bm-slow chunks
  // GEMM2: M=8192,N=1024,K=4096  BM=128,BN=256, grid 256, bn-slow chunks
  //        (A re-read 4x not 8x; 2MB B-panel L2-resident per XCD chunk)
  // expert 0
  gemm16<256, 256, true,  true,  true,  unsigned short><<<(M/256)*(F/256), 512, 0, stream>>>(xb,  w1t,                 x, b1, 0, h,   M, F, D);
  gemm16<128, 256, false, false, false, unsigned short><<<(M/128)*(D/256), 512, 0, stream>>>(h,   w2t,                 x, b2, 0, x1b, M, D, F);
  // expert 1
  gemm16<256, 256, true,  true,  true,  unsigned short><<<(M/256)*(F/256), 512, 0, stream>>>(x1b, w1t + (size_t)F * D, x, b1, 1, h,   M, F, D);
  gemm16<128, 256, false, false, false, float         ><<<(M/128)*(D/256), 512, 0, stream>>>(h,   w2t + (size_t)D * F, x, b2, 1, out, M, D, F);
}

// Round 7
// 338.142 us; speedup vs baseline: 1.1631x; 1.0445x over previous
//
#include <hip/hip_runtime.h>
#include <hip/hip_bf16.h>
#include <stdint.h>
#include <type_traits>

// ---------------------------------------------------------------------------
// MultiExpertMoELayer: opcode-routed 2-stage FFN chain.
//   op = argmax(x[0,0,0:8]);  for e in 0..1: x = gelu(x@W1[op,e]+b1)@W2[op,e]+b2
// Round 7: SYNC-STRUCTURE A/B vs R6 (geometry/staging/numerics identical).
//   R2-R6 all landed 350-393us (~39% of 16x16 ceiling); common denominator
//   was the lockstep phase skeleton {reads;SBAR;LGKM0;SCHEDB;MFMA;SCHEDB;SBAR}.
//   m141: sched_barrier(0) pinning = -40%; m97 asm: compiler emits fine
//   lgkmcnt(4/3/1/0) per-frag on its own (better than blanket LGKM0).
//   -> Remove ALL per-phase sync (9 barriers+3 SCHEDB per K-tile);
//      keep only the 2 load-bearing barriers per K-tile:
//        stage_all(t+1) -> vmcnt(S) -> SBAR -> [compiler-scheduled body]
//        -> lgkmcnt(0) -> SBAR
//      Counted vmcnt never drains mid-loop (T4); raw s_barrier (no implicit
//      vmcnt(0) drain, unlike __syncthreads -- the m97 stall).
// Canary: absmax must stay exactly 0.01171875 (accumulation DAG unchanged).
// ---------------------------------------------------------------------------

typedef __attribute__((ext_vector_type(8))) short short8;   // 8 x bf16 (4 VGPR)
typedef __attribute__((ext_vector_type(4))) float f32x4;    // MFMA accum

#define LGKM0  asm volatile("s_waitcnt lgkmcnt(0)" ::: "memory")
#define SBAR   __builtin_amdgcn_s_barrier()

template<int VM> __device__ __forceinline__ void wait_vm() {
  if constexpr (VM == 8)      asm volatile("s_waitcnt vmcnt(8)" ::: "memory");
  else if constexpr (VM == 6) asm volatile("s_waitcnt vmcnt(6)" ::: "memory");
  else                        asm volatile("s_waitcnt vmcnt(0)" ::: "memory");
}

__device__ __forceinline__ unsigned short f2bf(float f) {
  union { float f; uint32_t u; } v; v.f = f;
  return (unsigned short)((v.u + 0x7fffu + ((v.u >> 16) & 1u)) >> 16);  // RNE
}

// jax.nn.gelu(approximate=True): 0.5x(1+tanh(sqrt(2/pi)(x+0.044715x^3)))
__device__ __forceinline__ float gelu_tanh(float x) {
  float u = 0.7978845608028654f * (x + 0.044715f * x * x * x);
  float e = __expf(2.0f * u);
  float t = 1.0f - 2.0f / (e + 1.0f);   // tanh(u), safe at +/-inf
  return 0.5f * x * (1.0f + t);
}

__device__ __forceinline__ void gload_lds16(const void* g, void* l) {
  __builtin_amdgcn_global_load_lds(
      (const __attribute__((address_space(1))) void*)g,
      (__attribute__((address_space(3))) void*)l, 16, 0, 0);
}

// op = argmax(x[0,0,0:8]), first-max wins (matches jnp.argmax). Uniform,
// 8 L2-hot scalar loads -- cheap enough to recompute per block.
__device__ __forceinline__ int compute_op(const float* __restrict__ x) {
  int best = 0; float bv = x[0];
#pragma unroll
  for (int i = 1; i < 8; ++i) { float v = x[i]; if (v > bv) { bv = v; best = i; } }
  return best;
}

// --------------------------- fused prep kernel ------------------------------
// blocks [0, 4096)        : x fp32 -> bf16 (8 elems/thread)
// blocks [4096, 4096+4096): 4 transpose+cvt jobs of 1024 blocks each
__global__ __launch_bounds__(256) void prep_kernel(
    const float* __restrict__ x, const float* __restrict__ W1,
    const float* __restrict__ W2,
    unsigned short* __restrict__ xb, unsigned short* __restrict__ w1t,
    unsigned short* __restrict__ w2t) {
  __shared__ float tile[64][65];
  const int bid = blockIdx.x;
  const int t = threadIdx.x;
  if (bid < 4096) {
    const int i = bid * 256 + t;          // group-of-8 index
    const float4* xv = (const float4*)x;
    float4 v0 = xv[i * 2], v1 = xv[i * 2 + 1];
    ushort4 o0, o1;
    o0.x = f2bf(v0.x); o0.y = f2bf(v0.y); o0.z = f2bf(v0.z); o0.w = f2bf(v0.w);
    o1.x = f2bf(v1.x); o1.y = f2bf(v1.y); o1.z = f2bf(v1.z); o1.w = f2bf(v1.w);
    ((ushort4*)xb)[i * 2] = o0; ((ushort4*)xb)[i * 2 + 1] = o1;
    return;
  }
  const int op = compute_op(x);
  const int j = bid - 4096;
  const int job = j >> 10, w = j & 1023;
  const int e = job & 1;
  const bool isW1 = (job < 2);
  const int R = isW1 ? 1024 : 4096;
  const int C = isW1 ? 4096 : 1024;
  const float* W = (isW1 ? W1 : W2) + ((size_t)op * 2 + (size_t)e) * (size_t)R * C;
  unsigned short* dst0 = (isW1 ? w1t : w2t) + (size_t)e * 4096 * 1024;
  const int tc = w % (C >> 6), tr = w / (C >> 6);
  {
    const int r  = t >> 2;
    const int c0 = (t & 3) * 16;
    const float* src = W + (size_t)(tr * 64 + r) * C + tc * 64 + c0;
#pragma unroll
    for (int jj = 0; jj < 16; jj += 4) {
      float4 v = *(const float4*)(src + jj);
      tile[r][c0 + jj]     = v.x;
      tile[r][c0 + jj + 1] = v.y;
      tile[r][c0 + jj + 2] = v.z;
      tile[r][c0 + jj + 3] = v.w;
    }
  }
  __syncthreads();
  {
    const int c  = t >> 2;
    const int r0 = (t & 3) * 16;
    unsigned short* dp = dst0 + (size_t)(tc * 64 + c) * R + tr * 64 + r0;
#pragma unroll
    for (int jj = 0; jj < 16; jj += 4) {
      ushort4 o;
      o.x = f2bf(tile[r0 + jj][c]);
      o.y = f2bf(tile[r0 + jj + 1][c]);
      o.z = f2bf(tile[r0 + jj + 2][c]);
      o.w = f2bf(tile[r0 + jj + 3][c]);
      *(ushort4*)(dp + jj) = o;
    }
  }
}

// --------------------------- pipelined GEMM ---------------------------------
// C = A @ Bt^T + bias [,gelu].  A: [M][K] bf16, Bt: [N][K] bf16.
// 8 waves fixed 2M x 4N; per-wave (BM/2) x 64.
// LDS per buffer: A [BM][64] + B [BN][64] bf16; 16B chunk c of row r stored
// at c ^ (r&7) (both-sides swizzle with pre-swizzled staging source).

template<int BM, int BN>
__device__ __forceinline__ void stage_tile_all(
    const unsigned short* __restrict__ Ab,
    const unsigned short* __restrict__ Bb,
    int K, int kb, short* __restrict__ dst, int tid) {
  constexpr int SA = BM / 64, SB = BN / 64, ABK = BM * 64;
#pragma unroll
  for (int j = 0; j < SA; ++j) {
    const int ci = j * 512 + tid;
    const int row = ci >> 3;
    const int gc = (ci & 7) ^ (row & 7);
    gload_lds16(Ab + (size_t)row * K + kb + gc * 8, dst + ci * 8);
  }
#pragma unroll
  for (int j = 0; j < SB; ++j) {
    const int cj = j * 512 + tid;
    const int row = cj >> 3;
    const int gc = (cj & 7) ^ (row & 7);
    gload_lds16(Bb + (size_t)row * K + kb + gc * 8, dst + ABK + cj * 8);
  }
}

template<int BM, int BN, bool SLOW_BM, bool GELU, typename OUT_T>
__global__ __launch_bounds__(512, 2) void gemm16(
    const unsigned short* __restrict__ A,
    const unsigned short* __restrict__ Bt,
    const float* __restrict__ x_op,          // for inline op computation
    const float* __restrict__ bias_base,     // [8][2][N]
    int expert, OUT_T* __restrict__ Cout, int M, int N, int K)
{
  constexpr int BK = 64;
  constexpr int MR = BM / 32;             // 16-row frags per wave (8 or 4)
  constexpr int NR = 4;                   // 16-col frags per wave
  constexpr int S  = BM / 64 + BN / 64;   // stage instrs per K-tile (8 or 6)
  constexpr int BUF = (BM + BN) * BK;     // shorts per double-buffer half
  static_assert(BN == 256, "wave grid 2Mx4N assumes BN=256");
  __shared__ short smem[2 * BUF];

  const int tid  = threadIdx.x;
  const int wid  = tid >> 6, lane = tid & 63;
  const int wm   = wid >> 2, wn = wid & 3;
  const int lq   = lane >> 4, lr = lane & 15;

  // XCD-aware bijective swizzle (nwg % 8 == 0); slow index keeps the small
  // reused panel resident in the XCD's L2.
  const int nwg = gridDim.x;
  const int id  = blockIdx.x;
  const int s   = (id & 7) * (nwg >> 3) + (id >> 3);
  int bm, bn;
  if constexpr (SLOW_BM) { const int nbn = N / BN; bm = s / nbn; bn = s % nbn; }
  else                   { const int nbm = M / BM; bn = s / nbm; bm = s % nbm; }

  const unsigned short* Ab = A  + (size_t)bm * BM * K;
  const unsigned short* Bb = Bt + (size_t)bn * BN * K;

  f32x4 acc[MR][NR] = {};

  // prologue: stage all of K-tile 0 into buffer 0
  stage_tile_all<BM, BN>(Ab, Bb, K, 0, smem, tid);

  const int nkt = K / BK;
  for (int t = 0; t < nkt; ++t) {
    const char* cA = (const char*)(smem + (t & 1) * BUF);
    const char* cB = cA + BM * BK * 2;
    short* nxt = smem + ((t + 1) & 1) * BUF;

    // tile top: issue ALL of t+1's stages, counted wait for t's only (T4).
    if (t + 1 < nkt) { stage_tile_all<BM, BN>(Ab, Bb, K, (t + 1) * BK, nxt, tid); wait_vm<S>(); }
    else             { wait_vm<0>(); }
    SBAR;   // all waves' t-loads landed -> cur readable

    // ---- tile body: NO intra-tile sync; compiler schedules reads vs MFMAs
    //      with fine-grained lgkmcnt (m97-style). Loop nests kept only for
    //      register locality.
#pragma unroll
    for (int ks = 0; ks < 2; ++ks) {
      short8 bf[NR];
#pragma unroll
      for (int n = 0; n < NR; ++n) {
        const int rb = wn * 64 + n * 16 + lr;
        const int ch = ((ks << 2) | lq) ^ (rb & 7);
        bf[n] = *(const short8*)(cB + rb * 128 + ch * 16);
      }
#pragma unroll
      for (int mh = 0; mh < 2; ++mh) {
        short8 af[MR / 2];
#pragma unroll
        for (int mm = 0; mm < MR / 2; ++mm) {
          const int ra = wm * (BM / 2) + (mh * (MR / 2) + mm) * 16 + lr;
          const int ch = ((ks << 2) | lq) ^ (ra & 7);
          af[mm] = *(const short8*)(cA + ra * 128 + ch * 16);
        }
#pragma unroll
        for (int mm = 0; mm < MR / 2; ++mm)
#pragma unroll
          for (int n = 0; n < NR; ++n)
            acc[mh * (MR / 2) + mm][n] = __builtin_amdgcn_mfma_f32_16x16x32_bf16(
                af[mm], bf[n], acc[mh * (MR / 2) + mm][n], 0, 0, 0);
      }
    }

    // tile end: drain my ds_reads, then barrier -> next iter may overwrite cur
    LGKM0;
    SBAR;
  }

  // Epilogue: C/D layout col=lane&15, row=(lane>>4)*4+reg [m89-verified]
  const int op = compute_op(x_op);
  const float* bias = bias_base + ((size_t)op * 2 + (size_t)expert) * (size_t)N;
#pragma unroll
  for (int f = 0; f < MR; ++f) {
    const int grow0 = bm * BM + wm * (BM / 2) + f * 16 + lq * 4;
#pragma unroll
    for (int n = 0; n < NR; ++n) {
      const int gcol = bn * BN + wn * 64 + n * 16 + lr;
      const float bv = bias[gcol];
#pragma unroll
      for (int r = 0; r < 4; ++r) {
        float v = acc[f][n][r] + bv;
        if constexpr (GELU) v = gelu_tanh(v);
        const size_t off = (size_t)(grow0 + r) * N + gcol;
        if constexpr (std::is_same<OUT_T, float>::value) Cout[off] = v;
        else Cout[off] = f2bf(v);
      }
    }
  }
}

// --------------------------- launcher ---------------------------------------
extern "C" void kernel_launch(void* const* d_in, const int* in_sizes, int n_in,
                              void* d_out, int out_size, void* d_ws, size_t ws_size,
                              hipStream_t stream) {
  const float* x  = (const float*)d_in[0];
  const float* W1 = (const float*)d_in[1];   // [8][2][1024][4096]
  const float* b1 = (const float*)d_in[2];   // [8][2][4096]
  const float* W2 = (const float*)d_in[3];   // [8][2][4096][1024]
  const float* b2 = (const float*)d_in[4];   // [8][2][1024]
  float* out = (float*)d_out;

  const int D = 1024, F = 4096, M = 8192;    // M = B*S = 4*2048

  // ws layout: [xb 16.8MB][w1t 16.8MB][w2t 16.8MB][h 67.1MB]
  char* ws = (char*)d_ws;
  unsigned short* xb  = (unsigned short*)ws;
  unsigned short* w1t = (unsigned short*)(ws + (size_t)M * D * 2);
  unsigned short* w2t = (unsigned short*)(ws + (size_t)M * D * 2 + (size_t)2 * D * F * 2);
  unsigned short* h   = (unsigned short*)(ws + (size_t)M * D * 2 + (size_t)4 * D * F * 2);
  unsigned short* x1b = (unsigned short*)d_out;  // stage-0 output parked in d_out

  // one fused prep dispatch: cvt(x) + 4 transpose/cvt jobs
  prep_kernel<<<4096 + 4 * 1024, 256, 0, stream>>>(x, W1, W2, xb, w1t, w2t);

  // GEMM1: M=8192,N=4096,K=1024  BM=256,BN=256, grid 512, bm-slow chunks
  // GEMM2: M=8192,N=1024,K=4096  BM=128,BN=256, grid 256, bn-slow chunks
  // expert 0
  gemm16<256, 256, true,  true,  unsigned short><<<(M/256)*(F/256), 512, 0, stream>>>(xb,  w1t,                 x, b1, 0, h,   M, F, D);
  gemm16<128, 256, false, false, unsigned short><<<(M/128)*(D/256), 512, 0, stream>>>(h,   w2t,                 x, b2, 0, x1b, M, D, F);
  // expert 1
  gemm16<256, 256, true,  true,  unsigned short><<<(M/256)*(F/256), 512, 0, stream>>>(x1b, w1t + (size_t)F * D, x, b1, 1, h,   M, F, D);
  gemm16<128, 256, false, false, float         ><<<(M/128)*(D/256), 512, 0, stream>>>(h,   w2t + (size_t)D * F, x, b2, 1, out, M, D, F);
}